// Round 1
// baseline (39.481 us; speedup 1.0000x reference)
//
#include <hip/hip_runtime.h>

// NonLocalMean: x (4,64,128,128) fp32, K=7 (rad 3), HEADS=4 -> mid=16.
// Per (b,g,h,w): A_p = ||win_p - ctr||^2 over 16 ch, softmax(-A) over p=49,
// y = sum_p softmax_p * win_p, out = x + y. Zero padding => OOB windows are
// zero vectors that DO participate in the softmax denominator.
//
// Design: one thread per (pixel, head). 16x16 tile + halo 3 staged in LDS
// (22*22*16 fp32 ~31KB -> 4 blocks/CU). Pixel-major LDS layout, float4
// chunks XOR-swizzled to break the stride-64B bank pattern. ||n||^2
// precomputed per pixel (the ||ctr||^2 term cancels in softmax). Single
// pass over the 49 offsets with branchless online softmax (no second LDS
// read of the neighborhood).

#define TILE 16
#define RAD  3
#define HALO (TILE + 2 * RAD)     // 22
#define MID  16
#define NPIX (HALO * HALO)        // 484
#define IMG  128
#define HW   (IMG * IMG)

__device__ __forceinline__ int swz(int pix, int k) {
    // position of chunk k within pixel's 4 float4 slots; involution.
    return k ^ (pix & 3) ^ ((pix >> 2) & 1);
}

__global__ __launch_bounds__(256, 4)
void nlm_kernel(const float* __restrict__ x, float* __restrict__ out) {
    const int g   = blockIdx.z & 3;
    const int b   = blockIdx.z >> 2;
    const int tx0 = blockIdx.x * TILE;
    const int ty0 = blockIdx.y * TILE;

    __shared__ float lds[NPIX * MID];   // swizzled float4 chunks per pixel
    __shared__ float nn_lds[NPIX];      // ||n||^2 per pixel

    const int tid = threadIdx.x;
    const float* xb = x + (size_t)(b * 64 + g * MID) * HW;

    // ---- stage tile + halo (zero-filled OOB) into LDS, swizzled ----
    for (int i = tid; i < NPIX * MID; i += 256) {
        const int c   = i / NPIX;
        const int pix = i - c * NPIX;
        const int yy  = pix / HALO;
        const int xx  = pix - yy * HALO;
        const int gy  = ty0 + yy - RAD;
        const int gx  = tx0 + xx - RAD;
        float v = 0.0f;
        if ((unsigned)gy < (unsigned)IMG && (unsigned)gx < (unsigned)IMG)
            v = xb[c * HW + gy * IMG + gx];
        lds[pix * MID + swz(pix, c >> 2) * 4 + (c & 3)] = v;
    }
    __syncthreads();

    // ---- per-pixel squared norms ----
    for (int pix = tid; pix < NPIX; pix += 256) {
        float ss = 0.0f;
        #pragma unroll
        for (int c = 0; c < MID; ++c) {
            const float v = lds[pix * MID + swz(pix, c >> 2) * 4 + (c & 3)];
            ss = fmaf(v, v, ss);
        }
        nn_lds[pix] = ss;
    }
    __syncthreads();

    // ---- main: one pixel per thread ----
    const int lx = tid & 15;
    const int ly = tid >> 4;
    const int cp = (ly + RAD) * HALO + (lx + RAD);

    float ctr[MID];
    #pragma unroll
    for (int k = 0; k < 4; ++k) {
        const float4 v = *reinterpret_cast<const float4*>(&lds[cp * MID + swz(cp, k) * 4]);
        ctr[4 * k + 0] = v.x; ctr[4 * k + 1] = v.y;
        ctr[4 * k + 2] = v.z; ctr[4 * k + 3] = v.w;
    }

    float acc[MID];
    #pragma unroll
    for (int c = 0; c < MID; ++c) acc[c] = 0.0f;
    float m = -1.0e30f, s = 0.0f;

    #pragma unroll
    for (int dy = 0; dy < 7; ++dy) {
        #pragma unroll
        for (int dx = 0; dx < 7; ++dx) {
            const int pix = (ly + dy) * HALO + (lx + dx);
            float nb[MID];
            #pragma unroll
            for (int k = 0; k < 4; ++k) {
                const float4 v = *reinterpret_cast<const float4*>(&lds[pix * MID + swz(pix, k) * 4]);
                nb[4 * k + 0] = v.x; nb[4 * k + 1] = v.y;
                nb[4 * k + 2] = v.z; nb[4 * k + 3] = v.w;
            }
            float dot = 0.0f;
            #pragma unroll
            for (int c = 0; c < MID; ++c) dot = fmaf(nb[c], ctr[c], dot);
            // -A_p (up to the constant ||ctr||^2, which cancels in softmax)
            const float a  = fmaf(2.0f, dot, -nn_lds[pix]);
            const float mn = fmaxf(m, a);
            const float scl = __expf(m - mn);   // 1.0 when max unchanged
            const float w   = __expf(a - mn);
            s = fmaf(s, scl, w);
            #pragma unroll
            for (int c = 0; c < MID; ++c)
                acc[c] = fmaf(acc[c], scl, w * nb[c]);
            m = mn;
        }
    }

    const float inv = 1.0f / s;
    float* ob = out + (size_t)(b * 64 + g * MID) * HW
                    + (size_t)(ty0 + ly) * IMG + (tx0 + lx);
    #pragma unroll
    for (int c = 0; c < MID; ++c)
        ob[c * HW] = fmaf(acc[c], inv, ctr[c]);
}

extern "C" void kernel_launch(void* const* d_in, const int* in_sizes, int n_in,
                              void* d_out, int out_size, void* d_ws, size_t ws_size,
                              hipStream_t stream) {
    const float* x = (const float*)d_in[0];
    float* out = (float*)d_out;
    dim3 grid(IMG / TILE, IMG / TILE, 16);   // 8 x 8 x (B=4 * HEADS=4) = 1024 blocks
    nlm_kernel<<<grid, 256, 0, stream>>>(x, out);
}

// Round 2
// 34.675 us; speedup vs baseline: 1.1386x; 1.1386x over previous
//
#include <hip/hip_runtime.h>

// NonLocalMean: x (4,64,128,128) fp32, K=7 (rad 3), HEADS=4 -> mid=16.
// w_p = exp(2<n_p,c> - ||n_p||^2 - ||c||^2) = exp(-||n_p - c||^2) <= 1,
// exact softmax max is 0 (attained at the window center) -> no online rescale.
// out = x + (sum_p w_p * n_p) / (sum_p w_p). Zero padding => OOB patches are
// zero vectors (w = exp(-||c||^2)) that participate in the denominator.
//
// LDS layout: 80B pixel record = 16 ch + ||n||^2 + 3 pad dwords. 80/16=5 is
// odd -> ds_read_b128 bank-groups (5*pix+k)%8 cover all 8 groups over any 8
// consecutive pixels: conflict-free with NO swizzle math. All 49*5 reads per
// thread are base + compile-time offset -> fold into ds_read imm offsets.
// 484*80 = 38720B LDS -> exactly 4 blocks/CU.

#define TILE 16
#define RAD  3
#define HALO (TILE + 2 * RAD)     // 22
#define MID  16
#define NPIX (HALO * HALO)        // 484
#define IMG  128
#define HW   (IMG * IMG)
#define PSTR 20                   // dwords per pixel record (80 B)

__global__ __launch_bounds__(256, 4)
void nlm_kernel(const float* __restrict__ x, float* __restrict__ out) {
    const int g   = blockIdx.z & 3;
    const int b   = blockIdx.z >> 2;
    const int tx0 = blockIdx.x * TILE;
    const int ty0 = blockIdx.y * TILE;

    __shared__ __align__(16) float lds[NPIX * PSTR];

    const int tid = threadIdx.x;
    const float* xb = x + (size_t)(b * 64 + g * MID) * HW;

    // ---- stage tile + halo (zero-filled OOB) ----
    for (int i = tid; i < NPIX * MID; i += 256) {
        const int c   = i / NPIX;
        const int pix = i - c * NPIX;
        const int yy  = pix / HALO;
        const int xx  = pix - yy * HALO;
        const int gy  = ty0 + yy - RAD;
        const int gx  = tx0 + xx - RAD;
        float v = 0.0f;
        if ((unsigned)gy < (unsigned)IMG && (unsigned)gx < (unsigned)IMG)
            v = xb[c * HW + gy * IMG + gx];
        lds[pix * PSTR + c] = v;
    }
    __syncthreads();

    // ---- per-pixel squared norms into slot 16 of each record ----
    for (int pix = tid; pix < NPIX; pix += 256) {
        const float* p = &lds[pix * PSTR];
        float ss = 0.0f;
        #pragma unroll
        for (int k = 0; k < 4; ++k) {
            const float4 v = *reinterpret_cast<const float4*>(p + 4 * k);
            ss = fmaf(v.x, v.x, ss); ss = fmaf(v.y, v.y, ss);
            ss = fmaf(v.z, v.z, ss); ss = fmaf(v.w, v.w, ss);
        }
        lds[pix * PSTR + MID] = ss;
    }
    __syncthreads();

    // ---- main: one output pixel per thread ----
    const int lx = tid & 15;
    const int ly = tid >> 4;
    const float* base = &lds[(ly * HALO + lx) * PSTR];

    float ctr[MID];
    {
        const float* cp = base + (RAD * HALO + RAD) * PSTR;
        #pragma unroll
        for (int k = 0; k < 4; ++k) {
            const float4 v = *reinterpret_cast<const float4*>(cp + 4 * k);
            ctr[4 * k + 0] = v.x; ctr[4 * k + 1] = v.y;
            ctr[4 * k + 2] = v.z; ctr[4 * k + 3] = v.w;
        }
    }
    const float cc = base[(RAD * HALO + RAD) * PSTR + MID];

    float acc[MID];
    #pragma unroll
    for (int c = 0; c < MID; ++c) acc[c] = 0.0f;
    float s = 0.0f;

    #pragma unroll
    for (int dy = 0; dy < 7; ++dy) {
        #pragma unroll
        for (int dx = 0; dx < 7; ++dx) {
            const float* nbp = base + (dy * HALO + dx) * PSTR;  // const offset
            float nb[MID];
            #pragma unroll
            for (int k = 0; k < 4; ++k) {
                const float4 v = *reinterpret_cast<const float4*>(nbp + 4 * k);
                nb[4 * k + 0] = v.x; nb[4 * k + 1] = v.y;
                nb[4 * k + 2] = v.z; nb[4 * k + 3] = v.w;
            }
            const float nn = nbp[MID];
            float dot = 0.0f;
            #pragma unroll
            for (int c = 0; c < MID; ++c) dot = fmaf(nb[c], ctr[c], dot);
            const float w = __expf(fmaf(2.0f, dot, -(nn + cc)));  // <= 1, exact
            s += w;
            #pragma unroll
            for (int c = 0; c < MID; ++c) acc[c] = fmaf(w, nb[c], acc[c]);
        }
    }

    const float inv = 1.0f / s;
    float* ob = out + (size_t)(b * 64 + g * MID) * HW
                    + (size_t)(ty0 + ly) * IMG + (tx0 + lx);
    #pragma unroll
    for (int c = 0; c < MID; ++c)
        ob[c * HW] = fmaf(acc[c], inv, ctr[c]);
}

extern "C" void kernel_launch(void* const* d_in, const int* in_sizes, int n_in,
                              void* d_out, int out_size, void* d_ws, size_t ws_size,
                              hipStream_t stream) {
    const float* x = (const float*)d_in[0];
    float* out = (float*)d_out;
    dim3 grid(IMG / TILE, IMG / TILE, 16);   // 8 x 8 x (B=4 * HEADS=4)
    nlm_kernel<<<grid, 256, 0, stream>>>(x, out);
}

// Round 3
// 29.577 us; speedup vs baseline: 1.3349x; 1.1724x over previous
//
#include <hip/hip_runtime.h>

// NonLocalMean: x (4,64,128,128) fp32, K=7 (rad 3), HEADS=4 -> mid=16.
// w_p = exp(2<n_p,c> - ||n_p||^2 - ||c||^2) = exp(-||n_p-c||^2) <= 1; the
// softmax max is exactly 0 (center pixel) -> plain sum, no online rescale.
// out = x + (sum_p w_p n_p) / (sum_p w_p); zero-padded OOB patches are zero
// vectors that still contribute exp(-||c||^2) to the denominator.
//
// R3: each thread computes TWO vertically adjacent outputs. The stacked
// 7x7 windows overlap in 6 rows -> 56 LDS record reads serve 98 pairs
// (1.75x less LDS-read traffic, the R2 bottleneck). Norms live in a
// separate stride-1 array (kills the 8-way b32 conflict); staging does
// 4 coalesced global dword loads + one ds_write_b128 per channel-quad
// (kills the 8-way staging-write conflict). Record = 80 B (16ch + pad);
// 80/16=5 odd -> b128 chunk bank-groups (5*pix+k)%8 balanced, all main
// loop reads are base + compile-time immediate offset.

#define TW   16               // tile width
#define TH   32               // tile height (2 rows per thread)
#define RAD  3
#define HWD  22               // halo width  = TW + 6
#define HHT  38               // halo height = TH + 6
#define MID  16
#define NPIX (HWD * HHT)      // 836
#define PSTR 20               // record stride in dwords (80 B)
#define IMG  128
#define PLANE (IMG * IMG)

#define VISIT(RP, NP, WX, DO0, DO1)                                         \
    {                                                                       \
        const float* _rp = (RP) + (WX) * PSTR;                              \
        float nb[MID];                                                      \
        _Pragma("unroll")                                                   \
        for (int k = 0; k < 4; ++k) {                                       \
            const float4 v = *reinterpret_cast<const float4*>(_rp + 4 * k); \
            nb[4*k+0] = v.x; nb[4*k+1] = v.y;                               \
            nb[4*k+2] = v.z; nb[4*k+3] = v.w;                               \
        }                                                                   \
        const float nv = (NP)[WX];                                          \
        if (DO0) {                                                          \
            float dot = 0.f;                                                \
            _Pragma("unroll")                                               \
            for (int c = 0; c < MID; ++c) dot = fmaf(nb[c], ctr0[c], dot);  \
            const float w = __expf(fmaf(2.f, dot, -(nv + cc0)));            \
            s0 += w;                                                        \
            _Pragma("unroll")                                               \
            for (int c = 0; c < MID; ++c) acc0[c] = fmaf(w, nb[c], acc0[c]);\
        }                                                                   \
        if (DO1) {                                                          \
            float dot = 0.f;                                                \
            _Pragma("unroll")                                               \
            for (int c = 0; c < MID; ++c) dot = fmaf(nb[c], ctr1[c], dot);  \
            const float w = __expf(fmaf(2.f, dot, -(nv + cc1)));            \
            s1 += w;                                                        \
            _Pragma("unroll")                                               \
            for (int c = 0; c < MID; ++c) acc1[c] = fmaf(w, nb[c], acc1[c]);\
        }                                                                   \
    }

__global__ __launch_bounds__(256, 2)
void nlm_kernel(const float* __restrict__ x, float* __restrict__ out) {
    const int g   = blockIdx.z & 3;
    const int b   = blockIdx.z >> 2;
    const int tx0 = blockIdx.x * TW;
    const int ty0 = blockIdx.y * TH;

    __shared__ __align__(16) float rec[NPIX * PSTR];  // 66,880 B
    __shared__ float nn[NPIX];                        //  3,344 B

    const int tid = threadIdx.x;
    const float* xb = x + (size_t)(b * 64 + g * MID) * PLANE;

    // ---- stage halo: per item = (channel-quad, pixel) ----
    for (int i = tid; i < 4 * NPIX; i += 256) {
        const int cq  = i / NPIX;            // 0..3
        const int pix = i - cq * NPIX;       // consecutive per lane
        const int yy  = pix / HWD;
        const int xx  = pix - yy * HWD;
        const int gy  = ty0 + yy - RAD;
        const int gx  = tx0 + xx - RAD;
        float4 v = make_float4(0.f, 0.f, 0.f, 0.f);
        if ((unsigned)gy < (unsigned)IMG && (unsigned)gx < (unsigned)IMG) {
            const float* p = xb + (size_t)(4 * cq) * PLANE + gy * IMG + gx;
            v.x = p[0];         v.y = p[PLANE];
            v.z = p[2 * PLANE]; v.w = p[3 * PLANE];
        }
        *reinterpret_cast<float4*>(&rec[pix * PSTR + 4 * cq]) = v;
    }
    __syncthreads();

    // ---- per-pixel squared norms (separate stride-1 array) ----
    for (int pix = tid; pix < NPIX; pix += 256) {
        const float* p = &rec[pix * PSTR];
        float ss = 0.f;
        #pragma unroll
        for (int k = 0; k < 4; ++k) {
            const float4 v = *reinterpret_cast<const float4*>(p + 4 * k);
            ss = fmaf(v.x, v.x, ss); ss = fmaf(v.y, v.y, ss);
            ss = fmaf(v.z, v.z, ss); ss = fmaf(v.w, v.w, ss);
        }
        nn[pix] = ss;
    }
    __syncthreads();

    // ---- main: two vertically adjacent outputs per thread ----
    const int lx  = tid & 15;
    const int ly  = tid >> 4;                 // 0..15 -> rows 2ly, 2ly+1
    const int p00 = (2 * ly) * HWD + lx;      // window row 0 (out0), col 0

    float ctr0[MID], ctr1[MID];
    {
        const float* c0 = &rec[(p00 + 3 * HWD + 3) * PSTR];
        #pragma unroll
        for (int k = 0; k < 4; ++k) {
            const float4 v0 = *reinterpret_cast<const float4*>(c0 + 4 * k);
            const float4 v1 = *reinterpret_cast<const float4*>(c0 + HWD * PSTR + 4 * k);
            ctr0[4*k+0] = v0.x; ctr0[4*k+1] = v0.y;
            ctr0[4*k+2] = v0.z; ctr0[4*k+3] = v0.w;
            ctr1[4*k+0] = v1.x; ctr1[4*k+1] = v1.y;
            ctr1[4*k+2] = v1.z; ctr1[4*k+3] = v1.w;
        }
    }
    const float cc0 = nn[p00 + 3 * HWD + 3];
    const float cc1 = nn[p00 + 4 * HWD + 3];

    float acc0[MID], acc1[MID];
    #pragma unroll
    for (int c = 0; c < MID; ++c) { acc0[c] = 0.f; acc1[c] = 0.f; }
    float s0 = 0.f, s1 = 0.f;

    // wy = 0: feeds out0 only
    {
        const float* rp = &rec[p00 * PSTR];
        const float* np = &nn[p00];
        #pragma unroll
        for (int wx = 0; wx < 7; ++wx) VISIT(rp, np, wx, true, false);
    }
    // wy = 1..6: shared band, feeds both outputs
    #pragma unroll 2
    for (int wy = 1; wy < 7; ++wy) {
        const float* rp = &rec[(p00 + wy * HWD) * PSTR];
        const float* np = &nn[p00 + wy * HWD];
        #pragma unroll
        for (int wx = 0; wx < 7; ++wx) VISIT(rp, np, wx, true, true);
    }
    // wy = 7: feeds out1 only
    {
        const float* rp = &rec[(p00 + 7 * HWD) * PSTR];
        const float* np = &nn[p00 + 7 * HWD];
        #pragma unroll
        for (int wx = 0; wx < 7; ++wx) VISIT(rp, np, wx, false, true);
    }

    const float i0 = 1.f / s0;
    const float i1 = 1.f / s1;
    float* ob = out + (size_t)(b * 64 + g * MID) * PLANE
                    + (size_t)(ty0 + 2 * ly) * IMG + (tx0 + lx);
    #pragma unroll
    for (int c = 0; c < MID; ++c) {
        ob[c * PLANE]       = fmaf(acc0[c], i0, ctr0[c]);
        ob[c * PLANE + IMG] = fmaf(acc1[c], i1, ctr1[c]);
    }
}

extern "C" void kernel_launch(void* const* d_in, const int* in_sizes, int n_in,
                              void* d_out, int out_size, void* d_ws, size_t ws_size,
                              hipStream_t stream) {
    const float* x = (const float*)d_in[0];
    float* out = (float*)d_out;
    dim3 grid(IMG / TW, IMG / TH, 16);   // 8 x 4 x (B=4 * HEADS=4) = 512 blocks
    nlm_kernel<<<grid, 256, 0, stream>>>(x, out);
}